// Round 1
// baseline (12072.100 us; speedup 1.0000x reference)
//
#include <hip/hip_runtime.h>
#include <hip/hip_bf16.h>
#include <math.h>

#define N_NODES 50000
#define N_EDGES 800000
// F_IN = HID = 128, C = 40

// ---------------- degree / norm ----------------
__global__ void deg_init_k(float* __restrict__ deg) {
    int i = blockIdx.x * 256 + threadIdx.x;
    if (i < N_NODES) deg[i] = 1.0f;  // self-loop contributes 1
}

__global__ void deg_accum_k(const int* __restrict__ dst, float* __restrict__ deg) {
    int e = blockIdx.x * 256 + threadIdx.x;
    if (e < N_EDGES) atomicAdd(&deg[dst[e]], 1.0f);
}

__global__ void dinv_k(float* __restrict__ deg) {
    int i = blockIdx.x * 256 + threadIdx.x;
    if (i < N_NODES) deg[i] = rsqrtf(deg[i]);  // deg >= 1 always
}

// ---------------- GEMM: Y[N x FOUT] = X[N x 128] @ W[128 x FOUT] ----------------
template <int FOUT>
__global__ __launch_bounds__(256) void gemm_k(const float* __restrict__ X,
                                              const float* __restrict__ W,
                                              float* __restrict__ Y) {
    constexpr int K = 128, KT = 32;
    constexpr int TILE = 16 * FOUT;
    constexpr int ACC = (TILE + 255) / 256;
    __shared__ float sX[16 * KT];
    __shared__ float sW[KT * FOUT];
    const int row0 = blockIdx.x * 16;  // 3125 blocks * 16 = 50000 exactly
    const int tid = threadIdx.x;

    float acc[ACC];
#pragma unroll
    for (int a = 0; a < ACC; a++) acc[a] = 0.0f;

    for (int kt = 0; kt < K; kt += KT) {
        for (int li = tid; li < 16 * KT; li += 256) {
            int r = li >> 5, kk = li & 31;
            sX[li] = X[(size_t)(row0 + r) * K + kt + kk];
        }
        for (int li = tid; li < KT * FOUT; li += 256) {
            int kk = li / FOUT, j = li % FOUT;  // FOUT is compile-time
            sW[li] = W[(size_t)(kt + kk) * FOUT + j];
        }
        __syncthreads();
#pragma unroll
        for (int a = 0; a < ACC; a++) {
            int idx = tid + a * 256;
            if (idx < TILE) {
                int r = idx / FOUT, j = idx % FOUT;
                float s = acc[a];
#pragma unroll
                for (int kk = 0; kk < KT; kk++)
                    s = fmaf(sX[r * KT + kk], sW[kk * FOUT + j], s);
                acc[a] = s;
            }
        }
        __syncthreads();
    }
#pragma unroll
    for (int a = 0; a < ACC; a++) {
        int idx = tid + a * 256;
        if (idx < TILE) {
            int r = idx / FOUT, j = idx % FOUT;
            Y[(size_t)(row0 + r) * FOUT + j] = acc[a];
        }
    }
}

// ---------------- aggregation ----------------
// out[i][f] = XW[i][f]*dinv[i]^2 + b[f]   (self-loop + bias, full coverage)
template <int F>
__global__ void agg_init_k(const float* __restrict__ XW, const float* __restrict__ dinv,
                           const float* __restrict__ b, float* __restrict__ out) {
    int idx = blockIdx.x * 256 + threadIdx.x;
    if (idx < N_NODES * F) {
        int i = idx / F, f = idx % F;
        float di = dinv[i];
        out[idx] = fmaf(XW[idx], di * di, b[f]);
    }
}

// out[dst][fg..fg+3] += XW[src][fg..fg+3] * dinv[src]*dinv[dst]
template <int F>
__global__ void agg_edge_k(const float* __restrict__ XW, const float* __restrict__ dinv,
                           const int* __restrict__ src, const int* __restrict__ dst,
                           float* __restrict__ out) {
    int e = blockIdx.x * 256 + threadIdx.x;
    if (e >= N_EDGES) return;
    int fg = blockIdx.y * 4;
    int s = src[e], d = dst[e];
    float w = dinv[s] * dinv[d];
    const float4 v = *reinterpret_cast<const float4*>(&XW[(size_t)s * F + fg]);
    float* o = &out[(size_t)d * F + fg];
    atomicAdd(o + 0, v.x * w);
    atomicAdd(o + 1, v.y * w);
    atomicAdd(o + 2, v.z * w);
    atomicAdd(o + 3, v.w * w);
}

__global__ void relu_k(float* __restrict__ x, int n) {
    int i = blockIdx.x * 256 + threadIdx.x;
    if (i < n) x[i] = fmaxf(x[i], 0.0f);
}

// ---------------- log-softmax over C=40, one wave (64 lanes) per node ----------------
__global__ void logsoftmax_k(const float* __restrict__ in, float* __restrict__ out) {
    constexpr int C = 40;
    int gtid = blockIdx.x * 256 + threadIdx.x;
    int node = gtid >> 6;
    int lane = threadIdx.x & 63;
    if (node >= N_NODES) return;
    float v = (lane < C) ? in[(size_t)node * C + lane] : -INFINITY;
    float m = v;
#pragma unroll
    for (int o = 32; o > 0; o >>= 1) m = fmaxf(m, __shfl_xor(m, o));
    float e = (lane < C) ? expf(v - m) : 0.0f;
    float s = e;
#pragma unroll
    for (int o = 32; o > 0; o >>= 1) s += __shfl_xor(s, o);
    if (lane < C) out[(size_t)node * C + lane] = v - m - logf(s);
}

extern "C" void kernel_launch(void* const* d_in, const int* in_sizes, int n_in,
                              void* d_out, int out_size, void* d_ws, size_t ws_size,
                              hipStream_t stream) {
    const float* x  = (const float*)d_in[0];
    const float* W1 = (const float*)d_in[1];
    const float* b1 = (const float*)d_in[2];
    const float* W2 = (const float*)d_in[3];
    const float* b2 = (const float*)d_in[4];
    const float* W3 = (const float*)d_in[5];
    const float* b3 = (const float*)d_in[6];
    const int* ei   = (const int*)d_in[7];
    const int* srcp = ei;             // edge_index[0], length E
    const int* dstp = ei + N_EDGES;   // edge_index[1], length E
    float* out = (float*)d_out;

    float* deg  = (float*)d_ws;                       // N floats (becomes dinv in-place)
    float* bufA = deg + 50176;                        // N x 128
    float* bufB = bufA + (size_t)N_NODES * 128;       // N x 128

    const int NB_N   = (N_NODES + 255) / 256;
    const int NB_E   = (N_EDGES + 255) / 256;
    const int NB_NF  = (N_NODES * 128 + 255) / 256;
    const int NB_NC  = (N_NODES * 40 + 255) / 256;

    // normalization
    deg_init_k<<<NB_N, 256, 0, stream>>>(deg);
    deg_accum_k<<<NB_E, 256, 0, stream>>>(dstp, deg);
    dinv_k<<<NB_N, 256, 0, stream>>>(deg);

    // layer 1: h1 = relu(A_hat @ (x@W1) + b1)
    gemm_k<128><<<3125, 256, 0, stream>>>(x, W1, bufA);
    agg_init_k<128><<<NB_NF, 256, 0, stream>>>(bufA, deg, b1, bufB);
    agg_edge_k<128><<<dim3(NB_E, 32), 256, 0, stream>>>(bufA, deg, srcp, dstp, bufB);
    relu_k<<<NB_NF, 256, 0, stream>>>(bufB, N_NODES * 128);

    // layer 2: h2 = relu(A_hat @ (h1@W2) + b2)
    gemm_k<128><<<3125, 256, 0, stream>>>(bufB, W2, bufA);
    agg_init_k<128><<<NB_NF, 256, 0, stream>>>(bufA, deg, b2, bufB);
    agg_edge_k<128><<<dim3(NB_E, 32), 256, 0, stream>>>(bufA, deg, srcp, dstp, bufB);
    relu_k<<<NB_NF, 256, 0, stream>>>(bufB, N_NODES * 128);

    // layer 3: logits = A_hat @ (h2@W3) + b3
    gemm_k<40><<<3125, 256, 0, stream>>>(bufB, W3, bufA);
    agg_init_k<40><<<NB_NC, 256, 0, stream>>>(bufA, deg, b3, bufB);
    agg_edge_k<40><<<dim3(NB_E, 10), 256, 0, stream>>>(bufA, deg, srcp, dstp, bufB);

    // log-softmax -> d_out
    logsoftmax_k<<<(N_NODES * 64 + 255) / 256, 256, 0, stream>>>(bufB, out);
}

// Round 2
// 554.104 us; speedup vs baseline: 21.7867x; 21.7867x over previous
//
#include <hip/hip_runtime.h>
#include <hip/hip_bf16.h>
#include <math.h>

#define N_NODES 50000
#define N_EDGES 800000
// F_IN = HID = 128, C = 40

// ---------------- CSR build ----------------
__global__ void zero_cnt_k(int* __restrict__ cnt) {
    int i = blockIdx.x * 256 + threadIdx.x;
    if (i < N_NODES) cnt[i] = 0;
}

__global__ void hist_k(const int* __restrict__ dst, int* __restrict__ cnt) {
    int e = blockIdx.x * 256 + threadIdx.x;
    if (e < N_EDGES) atomicAdd(&cnt[dst[e]], 1);
}

__global__ void dinv_k(const int* __restrict__ cnt, float* __restrict__ dinv) {
    int i = blockIdx.x * 256 + threadIdx.x;
    if (i < N_NODES) dinv[i] = rsqrtf((float)(cnt[i] + 1));  // +1 self-loop
}

// single-block exclusive scan of cnt[N] -> rowptr[N] (+rowptr[N]=E), and
// cursor written back into cnt[] for the scatter pass.
__global__ __launch_bounds__(1024) void scan_k(int* __restrict__ cnt, int* __restrict__ rowptr) {
    __shared__ int wsum[16];
    __shared__ int chunk_base_s;
    const int tid = threadIdx.x;
    const int lane = tid & 63, wid = tid >> 6;
    int base = 0;
    for (int c0 = 0; c0 < N_NODES; c0 += 4096) {
        const int i0 = c0 + tid * 4;
        int v[4];
#pragma unroll
        for (int j = 0; j < 4; j++) v[j] = (i0 + j < N_NODES) ? cnt[i0 + j] : 0;
        int tsum = v[0] + v[1] + v[2] + v[3];
        // inclusive wave scan of tsum
        int sc = tsum;
#pragma unroll
        for (int o = 1; o < 64; o <<= 1) {
            int n = __shfl_up(sc, o);
            if (lane >= o) sc += n;
        }
        if (lane == 63) wsum[wid] = sc;
        __syncthreads();  // (A)
        if (wid == 0 && lane < 16) {
            int w = wsum[lane];
            int s2 = w;
#pragma unroll
            for (int o = 1; o < 16; o <<= 1) {
                int n = __shfl_up(s2, o);
                if (lane >= o) s2 += n;
            }
            wsum[lane] = s2 - w;  // exclusive
        }
        __syncthreads();  // (B)
        int excl = base + wsum[wid] + (sc - tsum);
#pragma unroll
        for (int j = 0; j < 4; j++) {
            if (i0 + j < N_NODES) {
                rowptr[i0 + j] = excl;
                cnt[i0 + j] = excl;  // cursor
                excl += v[j];
            }
        }
        if (tid == 1023) chunk_base_s = base + wsum[15] + sc;  // base + chunk total
        __syncthreads();  // (C)
        base = chunk_base_s;
        __syncthreads();  // (D) protect wsum/chunk_base_s for next iter
    }
    if (tid == 0) rowptr[N_NODES] = base;
}

__global__ void scatter_k(const int* __restrict__ src, const int* __restrict__ dst,
                          int* __restrict__ cursor, int* __restrict__ col) {
    int e = blockIdx.x * 256 + threadIdx.x;
    if (e < N_EDGES) {
        int pos = atomicAdd(&cursor[dst[e]], 1);
        col[pos] = src[e];
    }
}

// ---------------- GEMM: Y[N x FOUT] = X[N x 128] @ W[128 x FOUT] ----------------
template <int FOUT>
__global__ __launch_bounds__(256) void gemm_k(const float* __restrict__ X,
                                              const float* __restrict__ W,
                                              float* __restrict__ Y) {
    constexpr int K = 128, KT = 32;
    constexpr int TILE = 16 * FOUT;
    constexpr int ACC = (TILE + 255) / 256;
    __shared__ float sX[16 * KT];
    __shared__ float sW[KT * FOUT];
    const int row0 = blockIdx.x * 16;  // 3125 * 16 = 50000 exactly
    const int tid = threadIdx.x;

    float acc[ACC];
#pragma unroll
    for (int a = 0; a < ACC; a++) acc[a] = 0.0f;

    for (int kt = 0; kt < K; kt += KT) {
        for (int li = tid; li < 16 * KT; li += 256) {
            int r = li >> 5, kk = li & 31;
            sX[li] = X[(size_t)(row0 + r) * K + kt + kk];
        }
        for (int li = tid; li < KT * FOUT; li += 256) {
            int kk = li / FOUT, j = li % FOUT;
            sW[li] = W[(size_t)(kt + kk) * FOUT + j];
        }
        __syncthreads();
#pragma unroll
        for (int a = 0; a < ACC; a++) {
            int idx = tid + a * 256;
            if (idx < TILE) {
                int r = idx / FOUT, j = idx % FOUT;
                float s = acc[a];
#pragma unroll
                for (int kk = 0; kk < KT; kk++)
                    s = fmaf(sX[r * KT + kk], sW[kk * FOUT + j], s);
                acc[a] = s;
            }
        }
        __syncthreads();
    }
#pragma unroll
    for (int a = 0; a < ACC; a++) {
        int idx = tid + a * 256;
        if (idx < TILE) {
            int r = idx / FOUT, j = idx % FOUT;
            Y[(size_t)(row0 + r) * FOUT + j] = acc[a];
        }
    }
}

// ---------------- fused aggregation: one wave per node ----------------
// out[i] = relu?( sum_{e in CSR(i)} XW[col[e]] * dinv[col]*dinv[i]
//                 + XW[i]*dinv[i]^2 + b )
template <int F, bool RELU>
__global__ __launch_bounds__(256) void gather_k(const float* __restrict__ XW,
                                                const int* __restrict__ rowptr,
                                                const int* __restrict__ col,
                                                const float* __restrict__ dinv,
                                                const float* __restrict__ b,
                                                float* __restrict__ out) {
    const int node = (blockIdx.x * 256 + threadIdx.x) >> 6;
    const int lane = threadIdx.x & 63;
    if (node >= N_NODES) return;
    const float di = dinv[node];
    const int beg = rowptr[node], end = rowptr[node + 1];

    float acc0 = 0.f, acc1 = 0.f, acc0b = 0.f, acc1b = 0.f;
    int e = beg;
    for (; e + 1 < end; e += 2) {
        const int s0 = col[e], s1 = col[e + 1];
        const float w0 = dinv[s0] * di, w1 = dinv[s1] * di;
        if (F == 128) {
            acc0  += XW[(size_t)s0 * F + lane]      * w0;
            acc1  += XW[(size_t)s0 * F + 64 + lane] * w0;
            acc0b += XW[(size_t)s1 * F + lane]      * w1;
            acc1b += XW[(size_t)s1 * F + 64 + lane] * w1;
        } else if (lane < F) {
            acc0  += XW[(size_t)s0 * F + lane] * w0;
            acc0b += XW[(size_t)s1 * F + lane] * w1;
        }
    }
    if (e < end) {
        const int s0 = col[e];
        const float w0 = dinv[s0] * di;
        if (F == 128) {
            acc0 += XW[(size_t)s0 * F + lane]      * w0;
            acc1 += XW[(size_t)s0 * F + 64 + lane] * w0;
        } else if (lane < F) {
            acc0 += XW[(size_t)s0 * F + lane] * w0;
        }
    }
    acc0 += acc0b;
    acc1 += acc1b;

    const float wself = di * di;
    if (F == 128) {
        acc0 += XW[(size_t)node * F + lane] * wself;
        acc1 += XW[(size_t)node * F + 64 + lane] * wself;
        float o0 = acc0 + b[lane], o1 = acc1 + b[64 + lane];
        if (RELU) { o0 = fmaxf(o0, 0.f); o1 = fmaxf(o1, 0.f); }
        out[(size_t)node * F + lane] = o0;
        out[(size_t)node * F + 64 + lane] = o1;
    } else if (lane < F) {
        acc0 += XW[(size_t)node * F + lane] * wself;
        float o0 = acc0 + b[lane];
        if (RELU) o0 = fmaxf(o0, 0.f);
        out[(size_t)node * F + lane] = o0;
    }
}

// ---------------- log-softmax over C=40, one wave per node ----------------
__global__ void logsoftmax_k(const float* __restrict__ in, float* __restrict__ out) {
    constexpr int C = 40;
    int gtid = blockIdx.x * 256 + threadIdx.x;
    int node = gtid >> 6;
    int lane = threadIdx.x & 63;
    if (node >= N_NODES) return;
    float v = (lane < C) ? in[(size_t)node * C + lane] : -INFINITY;
    float m = v;
#pragma unroll
    for (int o = 32; o > 0; o >>= 1) m = fmaxf(m, __shfl_xor(m, o));
    float e = (lane < C) ? expf(v - m) : 0.0f;
    float s = e;
#pragma unroll
    for (int o = 32; o > 0; o >>= 1) s += __shfl_xor(s, o);
    if (lane < C) out[(size_t)node * C + lane] = v - m - logf(s);
}

extern "C" void kernel_launch(void* const* d_in, const int* in_sizes, int n_in,
                              void* d_out, int out_size, void* d_ws, size_t ws_size,
                              hipStream_t stream) {
    const float* x  = (const float*)d_in[0];
    const float* W1 = (const float*)d_in[1];
    const float* b1 = (const float*)d_in[2];
    const float* W2 = (const float*)d_in[3];
    const float* b2 = (const float*)d_in[4];
    const float* W3 = (const float*)d_in[5];
    const float* b3 = (const float*)d_in[6];
    const int* ei   = (const int*)d_in[7];
    const int* srcp = ei;             // edge_index[0]
    const int* dstp = ei + N_EDGES;   // edge_index[1]
    float* out = (float*)d_out;

    // workspace layout (4B elems)
    int*   cnt    = (int*)d_ws;                     // N (cursor after scan)
    int*   rowptr = cnt + 50176;                    // N+1
    float* dinv   = (float*)(rowptr + 50176);       // N
    int*   col    = (int*)(dinv + 50176);           // E
    float* bufA   = (float*)(col + 800768);         // N x 128
    float* bufB   = bufA + (size_t)N_NODES * 128;   // N x 128

    const int NB_N = (N_NODES + 255) / 256;
    const int NB_E = (N_EDGES + 255) / 256;
    const int NB_W = (N_NODES * 64 + 255) / 256;  // wave per node

    // CSR build + norms
    zero_cnt_k<<<NB_N, 256, 0, stream>>>(cnt);
    hist_k<<<NB_E, 256, 0, stream>>>(dstp, cnt);
    dinv_k<<<NB_N, 256, 0, stream>>>(cnt, dinv);
    scan_k<<<1, 1024, 0, stream>>>(cnt, rowptr);
    scatter_k<<<NB_E, 256, 0, stream>>>(srcp, dstp, cnt, col);

    // layer 1
    gemm_k<128><<<3125, 256, 0, stream>>>(x, W1, bufA);
    gather_k<128, true><<<NB_W, 256, 0, stream>>>(bufA, rowptr, col, dinv, b1, bufB);
    // layer 2
    gemm_k<128><<<3125, 256, 0, stream>>>(bufB, W2, bufA);
    gather_k<128, true><<<NB_W, 256, 0, stream>>>(bufA, rowptr, col, dinv, b2, bufB);
    // layer 3
    gemm_k<40><<<3125, 256, 0, stream>>>(bufB, W3, bufA);
    gather_k<40, false><<<NB_W, 256, 0, stream>>>(bufA, rowptr, col, dinv, b3, bufB);
    // log-softmax
    logsoftmax_k<<<NB_W, 256, 0, stream>>>(bufB, out);
}

// Round 3
// 429.848 us; speedup vs baseline: 28.0846x; 1.2891x over previous
//
#include <hip/hip_runtime.h>
#include <math.h>

#define N_NODES 50000
#define N_EDGES 800000
// F_IN = HID = 128, C = 40

typedef __attribute__((ext_vector_type(8))) short short8;
typedef __attribute__((ext_vector_type(4))) float f32x4;

__device__ __forceinline__ ushort f2bf(float f) {
    union { float f; uint u; } v; v.f = f;
    uint r = v.u + 0x7FFFu + ((v.u >> 16) & 1u);  // RNE
    return (ushort)(r >> 16);
}
__device__ __forceinline__ float bflo(uint p) {
    union { uint u; float f; } v; v.u = p << 16; return v.f;
}
__device__ __forceinline__ float bfhi(uint p) {
    union { uint u; float f; } v; v.u = p & 0xFFFF0000u; return v.f;
}

// ---------------- CSR build ----------------
__global__ void zero_cnt_k(int* __restrict__ cnt) {
    int i = blockIdx.x * 256 + threadIdx.x;
    if (i < N_NODES) cnt[i] = 0;
}

__global__ void hist_k(const int* __restrict__ dst, int* __restrict__ cnt) {
    int e = blockIdx.x * 256 + threadIdx.x;
    if (e < N_EDGES) atomicAdd(&cnt[dst[e]], 1);
}

__global__ void dinv_k(const int* __restrict__ cnt, float* __restrict__ dinv) {
    int i = blockIdx.x * 256 + threadIdx.x;
    if (i < N_NODES) dinv[i] = rsqrtf((float)(cnt[i] + 1));  // +1 self-loop
}

__global__ __launch_bounds__(1024) void scan_k(int* __restrict__ cnt, int* __restrict__ rowptr) {
    __shared__ int wsum[16];
    __shared__ int chunk_base_s;
    const int tid = threadIdx.x;
    const int lane = tid & 63, wid = tid >> 6;
    int base = 0;
    for (int c0 = 0; c0 < N_NODES; c0 += 4096) {
        const int i0 = c0 + tid * 4;
        int v[4];
#pragma unroll
        for (int j = 0; j < 4; j++) v[j] = (i0 + j < N_NODES) ? cnt[i0 + j] : 0;
        int tsum = v[0] + v[1] + v[2] + v[3];
        int sc = tsum;
#pragma unroll
        for (int o = 1; o < 64; o <<= 1) {
            int n = __shfl_up(sc, o);
            if (lane >= o) sc += n;
        }
        if (lane == 63) wsum[wid] = sc;
        __syncthreads();
        if (wid == 0 && lane < 16) {
            int w = wsum[lane];
            int s2 = w;
#pragma unroll
            for (int o = 1; o < 16; o <<= 1) {
                int n = __shfl_up(s2, o);
                if (lane >= o) s2 += n;
            }
            wsum[lane] = s2 - w;  // exclusive
        }
        __syncthreads();
        int excl = base + wsum[wid] + (sc - tsum);
#pragma unroll
        for (int j = 0; j < 4; j++) {
            if (i0 + j < N_NODES) {
                rowptr[i0 + j] = excl;
                cnt[i0 + j] = excl;  // cursor for scatter
                excl += v[j];
            }
        }
        if (tid == 1023) chunk_base_s = base + wsum[15] + sc;
        __syncthreads();
        base = chunk_base_s;
        __syncthreads();
    }
    if (tid == 0) rowptr[N_NODES] = base;
}

__global__ void scatter_k(const int* __restrict__ src, const int* __restrict__ dst,
                          int* __restrict__ cursor, int* __restrict__ col) {
    int e = blockIdx.x * 256 + threadIdx.x;
    if (e < N_EDGES) {
        int pos = atomicAdd(&cursor[dst[e]], 1);
        col[pos] = src[e];
    }
}

// ---------------- f32 -> bf16 convert (8 elems/thread) ----------------
__global__ void f32_to_bf16_k(const float* __restrict__ in, ushort* __restrict__ out) {
    int i = blockIdx.x * 256 + threadIdx.x;  // 800000 threads
    if (i >= N_NODES * 16) return;
    const float4* p = reinterpret_cast<const float4*>(in) + 2 * (size_t)i;
    float4 a = p[0], b = p[1];
    uint4 o;
    o.x = (uint)f2bf(a.x) | ((uint)f2bf(a.y) << 16);
    o.y = (uint)f2bf(a.z) | ((uint)f2bf(a.w) << 16);
    o.z = (uint)f2bf(b.x) | ((uint)f2bf(b.y) << 16);
    o.w = (uint)f2bf(b.z) | ((uint)f2bf(b.w) << 16);
    reinterpret_cast<uint4*>(out)[i] = o;
}

// ---------------- MFMA GEMM: Y[N x fout](bf16) = A[N x 128](bf16) @ W[128 x fout](f32) ----------------
// NT = number of 16-col output tiles (8 for fout=128, 3 for fout=40 padded to 48)
template <int NT>
__global__ __launch_bounds__(256) void gemm_mfma_k(const ushort* __restrict__ A,
                                                   const float* __restrict__ W,
                                                   ushort* __restrict__ Y,
                                                   const int fout) {
    // LDS holds W as pre-arranged bf16 MFMA B-fragments:
    // layout [(s*NT + t)*64 + lane]*8 + j, where k = 32*s + 8*(lane>>4) + j, n = 16*t + (lane&15)
    __shared__ ushort sB[4 * NT * 64 * 8];
    const int tid = threadIdx.x;
    constexpr int TOT = 4 * NT * 64 * 8;
    for (int i = tid; i < TOT; i += 256) {
        const int j = i & 7;
        const int l = (i >> 3) & 63;
        const int ts = i >> 9;  // s*NT + t
        const int t = ts % NT, s = ts / NT;
        const int k = 32 * s + 8 * (l >> 4) + j;
        const int n = 16 * t + (l & 15);
        sB[i] = (n < fout) ? f2bf(W[k * fout + n]) : (ushort)0;
    }
    __syncthreads();

    const int wid = tid >> 6, lane = tid & 63;
    const int tile = blockIdx.x * 4 + wid;      // 16-row tile; 3125 tiles total
    if (tile >= N_NODES / 16) return;
    const int row0 = tile * 16;
    const int r = row0 + (lane & 15);

    f32x4 acc[NT];
#pragma unroll
    for (int t = 0; t < NT; t++) acc[t] = (f32x4){0.f, 0.f, 0.f, 0.f};

#pragma unroll
    for (int s = 0; s < 4; s++) {
        short8 a = *reinterpret_cast<const short8*>(A + (size_t)r * 128 + 32 * s + 8 * (lane >> 4));
#pragma unroll
        for (int t = 0; t < NT; t++) {
            short8 b = *reinterpret_cast<const short8*>(&sB[((s * NT + t) * 64 + lane) * 8]);
            acc[t] = __builtin_amdgcn_mfma_f32_16x16x32_bf16(a, b, acc[t], 0, 0, 0);
        }
    }

    const int rl = 4 * (lane >> 4);  // D: row = (lane>>4)*4 + reg, col = lane&15
    const int cl = lane & 15;
#pragma unroll
    for (int t = 0; t < NT; t++) {
        const int c = 16 * t + cl;
        if (NT == 3 && c >= fout) continue;
#pragma unroll
        for (int g = 0; g < 4; g++)
            Y[(size_t)(row0 + rl + g) * fout + c] = f2bf(acc[t][g]);
    }
}

// ---------------- fused aggregation (F=128): one wave per node, bf16 in/out ----------------
template <bool RELU>
__global__ __launch_bounds__(256) void gather128_k(const ushort* __restrict__ XW,
                                                   const int* __restrict__ rowptr,
                                                   const int* __restrict__ col,
                                                   const float* __restrict__ dinv,
                                                   const float* __restrict__ bias,
                                                   ushort* __restrict__ out) {
    const int node = (blockIdx.x * 256 + threadIdx.x) >> 6;
    const int lane = threadIdx.x & 63;
    if (node >= N_NODES) return;
    const float di = dinv[node];
    const int beg = rowptr[node], end = rowptr[node + 1];
    const uint* XW32 = reinterpret_cast<const uint*>(XW);  // row stride 64 uints

    float a0 = 0.f, a1 = 0.f, c0 = 0.f, c1 = 0.f;
    int e = beg;
    for (; e + 1 < end; e += 2) {
        const int s0 = col[e], s1 = col[e + 1];
        const float w0 = dinv[s0] * di, w1 = dinv[s1] * di;
        const uint p0 = XW32[(size_t)s0 * 64 + lane];
        const uint p1 = XW32[(size_t)s1 * 64 + lane];
        a0 = fmaf(bflo(p0), w0, a0); a1 = fmaf(bfhi(p0), w0, a1);
        c0 = fmaf(bflo(p1), w1, c0); c1 = fmaf(bfhi(p1), w1, c1);
    }
    if (e < end) {
        const int s0 = col[e];
        const float w0 = dinv[s0] * di;
        const uint p0 = XW32[(size_t)s0 * 64 + lane];
        a0 = fmaf(bflo(p0), w0, a0); a1 = fmaf(bfhi(p0), w0, a1);
    }
    const uint ps = XW32[(size_t)node * 64 + lane];
    const float ws = di * di;
    a0 = fmaf(bflo(ps), ws, a0 + c0) + bias[2 * lane];
    a1 = fmaf(bfhi(ps), ws, a1 + c1) + bias[2 * lane + 1];
    if (RELU) { a0 = fmaxf(a0, 0.f); a1 = fmaxf(a1, 0.f); }
    reinterpret_cast<uint*>(out)[(size_t)node * 64 + lane] =
        (uint)f2bf(a0) | ((uint)f2bf(a1) << 16);
}

// ---------------- layer 3: gather (F=40, bf16 in) fused with log-softmax, f32 out ----------------
__global__ __launch_bounds__(256) void gather40_lsm_k(const ushort* __restrict__ XW,
                                                      const int* __restrict__ rowptr,
                                                      const int* __restrict__ col,
                                                      const float* __restrict__ dinv,
                                                      const float* __restrict__ bias,
                                                      float* __restrict__ out) {
    const int node = (blockIdx.x * 256 + threadIdx.x) >> 6;
    const int lane = threadIdx.x & 63;
    if (node >= N_NODES) return;
    const bool active = lane < 20;  // lane handles feats 2*lane, 2*lane+1
    const float di = dinv[node];
    const int beg = rowptr[node], end = rowptr[node + 1];
    const uint* XW32 = reinterpret_cast<const uint*>(XW);  // row stride 20 uints

    float a0 = 0.f, a1 = 0.f;
    for (int e = beg; e < end; e++) {
        const int s0 = col[e];
        const float w0 = dinv[s0] * di;
        if (active) {
            const uint p0 = XW32[(size_t)s0 * 20 + lane];
            a0 = fmaf(bflo(p0), w0, a0); a1 = fmaf(bfhi(p0), w0, a1);
        }
    }
    float v0 = -INFINITY, v1 = -INFINITY;
    if (active) {
        const uint ps = XW32[(size_t)node * 20 + lane];
        const float ws = di * di;
        v0 = fmaf(bflo(ps), ws, a0) + bias[2 * lane];
        v1 = fmaf(bfhi(ps), ws, a1) + bias[2 * lane + 1];
    }
    float m = fmaxf(v0, v1);
#pragma unroll
    for (int o = 32; o > 0; o >>= 1) m = fmaxf(m, __shfl_xor(m, o));
    float s = active ? (expf(v0 - m) + expf(v1 - m)) : 0.f;
#pragma unroll
    for (int o = 32; o > 0; o >>= 1) s += __shfl_xor(s, o);
    if (active) {
        const float ls = m + logf(s);
        float2 r; r.x = v0 - ls; r.y = v1 - ls;
        reinterpret_cast<float2*>(out)[(size_t)node * 20 + lane] = r;
    }
}

extern "C" void kernel_launch(void* const* d_in, const int* in_sizes, int n_in,
                              void* d_out, int out_size, void* d_ws, size_t ws_size,
                              hipStream_t stream) {
    const float* x  = (const float*)d_in[0];
    const float* W1 = (const float*)d_in[1];
    const float* b1 = (const float*)d_in[2];
    const float* W2 = (const float*)d_in[3];
    const float* b2 = (const float*)d_in[4];
    const float* W3 = (const float*)d_in[5];
    const float* b3 = (const float*)d_in[6];
    const int* ei   = (const int*)d_in[7];
    const int* srcp = ei;
    const int* dstp = ei + N_EDGES;
    float* out = (float*)d_out;

    // workspace (4B units for the int/f32 part, then two bf16 N x 128 buffers)
    int*    cnt    = (int*)d_ws;                    // 50176
    int*    rowptr = cnt + 50176;                   // 50176
    float*  dinv   = (float*)(rowptr + 50176);      // 50176
    int*    col    = (int*)(dinv + 50176);          // 800768
    ushort* B0     = (ushort*)(col + 800768);       // N*128 bf16 (16B aligned)
    ushort* B1     = B0 + (size_t)N_NODES * 128;    // N*128 bf16

    const int NB_N = (N_NODES + 255) / 256;
    const int NB_E = (N_EDGES + 255) / 256;
    const int NB_W = (N_NODES * 64) / 256;          // 12500: one wave per node

    // CSR + norms
    zero_cnt_k<<<NB_N, 256, 0, stream>>>(cnt);
    hist_k<<<NB_E, 256, 0, stream>>>(dstp, cnt);
    dinv_k<<<NB_N, 256, 0, stream>>>(cnt, dinv);
    scan_k<<<1, 1024, 0, stream>>>(cnt, rowptr);
    scatter_k<<<NB_E, 256, 0, stream>>>(srcp, dstp, cnt, col);

    // x -> bf16
    f32_to_bf16_k<<<3125, 256, 0, stream>>>(x, B0);

    // layer 1
    gemm_mfma_k<8><<<782, 256, 0, stream>>>(B0, W1, B1, 128);
    gather128_k<true><<<NB_W, 256, 0, stream>>>(B1, rowptr, col, dinv, b1, B0);
    // layer 2
    gemm_mfma_k<8><<<782, 256, 0, stream>>>(B0, W2, B1, 128);
    gather128_k<true><<<NB_W, 256, 0, stream>>>(B1, rowptr, col, dinv, b2, B0);
    // layer 3 (fout=40) + fused log-softmax
    gemm_mfma_k<3><<<782, 256, 0, stream>>>(B0, W3, B1, 40);
    gather40_lsm_k<<<NB_W, 256, 0, stream>>>(B1, rowptr, col, dinv, b3, out);
}

// Round 4
// 298.387 us; speedup vs baseline: 40.4579x; 1.4406x over previous
//
#include <hip/hip_runtime.h>
#include <math.h>

#define N_NODES 50000
#define N_EDGES 800000
#define BUCKET 64
// F_IN = HID = 128, C = 40

typedef __attribute__((ext_vector_type(8))) short short8;
typedef __attribute__((ext_vector_type(4))) float f32x4;

__device__ __forceinline__ ushort f2bf(float f) {
    union { float f; uint u; } v; v.f = f;
    uint r = v.u + 0x7FFFu + ((v.u >> 16) & 1u);  // RNE
    return (ushort)(r >> 16);
}
__device__ __forceinline__ float bflo(uint p) {
    union { uint u; float f; } v; v.u = p << 16; return v.f;
}
__device__ __forceinline__ float bfhi(uint p) {
    union { uint u; float f; } v; v.u = p & 0xFFFF0000u; return v.f;
}

// ---------------- bucketed CSR build ----------------
__global__ void zero_cnt_k(int* __restrict__ cnt) {
    int i = blockIdx.x * 256 + threadIdx.x;
    if (i < N_NODES) cnt[i] = 0;
}

// fused histogram + scatter into fixed-capacity buckets
__global__ void scatter_k(const int* __restrict__ src, const int* __restrict__ dst,
                          int* __restrict__ cnt, int* __restrict__ colb) {
    int e = blockIdx.x * 256 + threadIdx.x;
    if (e < N_EDGES) {
        int d = dst[e];
        int pos = atomicAdd(&cnt[d], 1);
        colb[(size_t)d * BUCKET + pos] = src[e];
    }
}

__global__ void dinv_k(const int* __restrict__ cnt, float* __restrict__ dinv) {
    int i = blockIdx.x * 256 + threadIdx.x;
    if (i < N_NODES) dinv[i] = rsqrtf((float)(cnt[i] + 1));  // +1 self-loop
}

// ---------------- MFMA GEMM: Y[N x fout](bf16) = A[N x 128] @ W[128 x fout](f32) ----------------
// 512 threads, 8 waves, each wave does 2 row-tiles (block = 256 rows).
// B-fragments in LDS with lane-permutation lp = (l&56)|((l+(l>>3))&7) -> conflict-free ds_read_b128.
template <int NT, bool CVT>
__global__ __launch_bounds__(512) void gemm_mfma_k(const void* __restrict__ Av,
                                                   const float* __restrict__ W,
                                                   ushort* __restrict__ Y,
                                                   const int fout) {
    __shared__ ushort sB[4 * NT * 64 * 8];
    const int tid = threadIdx.x;
    constexpr int FP = NT * 16;  // padded fout
    for (int i = tid; i < 128 * FP; i += 512) {
        const int k = i / FP, n = i % FP;           // coalesced W read (n fastest)
        const int s = k >> 5, r2 = (k >> 3) & 3, j = k & 7;
        const int t = n >> 4, nl = n & 15;
        const int l = r2 * 16 + nl;                 // logical lane of this fragment elem
        const int lp = (l & 56) | ((l + (l >> 3)) & 7);
        sB[(((s * NT + t) * 64) + lp) * 8 + j] = (n < fout) ? f2bf(W[k * fout + n]) : (ushort)0;
    }
    __syncthreads();

    const int wid = tid >> 6, lane = tid & 63;
    const int lp = (lane & 56) | ((lane + (lane >> 3)) & 7);
    const int t0 = blockIdx.x * 16 + wid * 2;       // row-tile ids (16 rows each)
    const int t1 = t0 + 1;
    const int t0c = min(t0, N_NODES / 16 - 1);
    const int t1c = min(t1, N_NODES / 16 - 1);

    f32x4 acc[2][NT];
#pragma unroll
    for (int u = 0; u < 2; u++)
#pragma unroll
        for (int t = 0; t < NT; t++) acc[u][t] = (f32x4){0.f, 0.f, 0.f, 0.f};

#pragma unroll
    for (int s = 0; s < 4; s++) {
        short8 a0, a1;
        const int ko = 32 * s + 8 * (lane >> 4);
        if (CVT) {
            const float* Af = (const float*)Av;
            const float4* p0 = reinterpret_cast<const float4*>(Af + (size_t)(t0c * 16 + (lane & 15)) * 128 + ko);
            const float4* p1 = reinterpret_cast<const float4*>(Af + (size_t)(t1c * 16 + (lane & 15)) * 128 + ko);
            float4 u0 = p0[0], u1 = p0[1], v0 = p1[0], v1 = p1[1];
            a0[0] = f2bf(u0.x); a0[1] = f2bf(u0.y); a0[2] = f2bf(u0.z); a0[3] = f2bf(u0.w);
            a0[4] = f2bf(u1.x); a0[5] = f2bf(u1.y); a0[6] = f2bf(u1.z); a0[7] = f2bf(u1.w);
            a1[0] = f2bf(v0.x); a1[1] = f2bf(v0.y); a1[2] = f2bf(v0.z); a1[3] = f2bf(v0.w);
            a1[4] = f2bf(v1.x); a1[5] = f2bf(v1.y); a1[6] = f2bf(v1.z); a1[7] = f2bf(v1.w);
        } else {
            const ushort* Ab = (const ushort*)Av;
            a0 = *reinterpret_cast<const short8*>(Ab + (size_t)(t0c * 16 + (lane & 15)) * 128 + ko);
            a1 = *reinterpret_cast<const short8*>(Ab + (size_t)(t1c * 16 + (lane & 15)) * 128 + ko);
        }
#pragma unroll
        for (int t = 0; t < NT; t++) {
            short8 b = *reinterpret_cast<const short8*>(&sB[(((s * NT + t) * 64) + lp) * 8]);
            acc[0][t] = __builtin_amdgcn_mfma_f32_16x16x32_bf16(a0, b, acc[0][t], 0, 0, 0);
            acc[1][t] = __builtin_amdgcn_mfma_f32_16x16x32_bf16(a1, b, acc[1][t], 0, 0, 0);
        }
    }

    const int rl = 4 * (lane >> 4), cl = lane & 15;  // D: row=(lane>>4)*4+reg, col=lane&15
#pragma unroll
    for (int u = 0; u < 2; u++) {
        const int tile = u ? t1 : t0;
        if (tile >= N_NODES / 16) continue;
        const int row0 = tile * 16;
#pragma unroll
        for (int t = 0; t < NT; t++) {
            const int c = 16 * t + cl;
            if (NT == 3 && c >= fout) continue;
#pragma unroll
            for (int g = 0; g < 4; g++)
                Y[(size_t)(row0 + rl + g) * fout + c] = f2bf(acc[u][t][g]);
        }
    }
}

// ---------------- fused aggregation (F=128): one wave/node, 4-edge unroll ----------------
template <bool RELU>
__global__ __launch_bounds__(256) void gather128_k(const ushort* __restrict__ XW,
                                                   const int* __restrict__ cnt,
                                                   const int* __restrict__ colb,
                                                   const float* __restrict__ dinv,
                                                   const float* __restrict__ bias,
                                                   ushort* __restrict__ out) {
    const int node = (blockIdx.x * 256 + threadIdx.x) >> 6;
    const int lane = threadIdx.x & 63;
    if (node >= N_NODES) return;
    const float di = dinv[node];
    const int n = cnt[node];
    const int4* bucket = reinterpret_cast<const int4*>(colb + (size_t)node * BUCKET);
    const uint* XW32 = reinterpret_cast<const uint*>(XW);  // row stride 64 uints

    float a0 = 0.f, a1 = 0.f, b0 = 0.f, b1 = 0.f;
    float c0 = 0.f, c1 = 0.f, d0 = 0.f, d1 = 0.f;
    int e = 0;
    for (; e + 4 <= n; e += 4) {
        const int4 s4 = bucket[e >> 2];
        const float w0 = dinv[s4.x] * di, w1 = dinv[s4.y] * di;
        const float w2 = dinv[s4.z] * di, w3 = dinv[s4.w] * di;
        const uint p0 = XW32[(size_t)s4.x * 64 + lane];
        const uint p1 = XW32[(size_t)s4.y * 64 + lane];
        const uint p2 = XW32[(size_t)s4.z * 64 + lane];
        const uint p3 = XW32[(size_t)s4.w * 64 + lane];
        a0 = fmaf(bflo(p0), w0, a0); a1 = fmaf(bfhi(p0), w0, a1);
        b0 = fmaf(bflo(p1), w1, b0); b1 = fmaf(bfhi(p1), w1, b1);
        c0 = fmaf(bflo(p2), w2, c0); c1 = fmaf(bfhi(p2), w2, c1);
        d0 = fmaf(bflo(p3), w3, d0); d1 = fmaf(bfhi(p3), w3, d1);
    }
    for (; e < n; e++) {
        const int s = colb[(size_t)node * BUCKET + e];
        const float w = dinv[s] * di;
        const uint p = XW32[(size_t)s * 64 + lane];
        a0 = fmaf(bflo(p), w, a0); a1 = fmaf(bfhi(p), w, a1);
    }
    const uint ps = XW32[(size_t)node * 64 + lane];
    const float ws = di * di;
    a0 = fmaf(bflo(ps), ws, (a0 + b0) + (c0 + d0)) + bias[2 * lane];
    a1 = fmaf(bfhi(ps), ws, (a1 + b1) + (c1 + d1)) + bias[2 * lane + 1];
    if (RELU) { a0 = fmaxf(a0, 0.f); a1 = fmaxf(a1, 0.f); }
    reinterpret_cast<uint*>(out)[(size_t)node * 64 + lane] =
        (uint)f2bf(a0) | ((uint)f2bf(a1) << 16);
}

// ---------------- layer 3: gather (F=40) + log-softmax, 3 edge-groups per wave ----------------
__global__ __launch_bounds__(256) void gather40_lsm_k(const ushort* __restrict__ XW,
                                                      const int* __restrict__ cnt,
                                                      const int* __restrict__ colb,
                                                      const float* __restrict__ dinv,
                                                      const float* __restrict__ bias,
                                                      float* __restrict__ out) {
    const int node = (blockIdx.x * 256 + threadIdx.x) >> 6;
    const int lane = threadIdx.x & 63;
    if (node >= N_NODES) return;
    const int g = lane < 20 ? 0 : (lane < 40 ? 1 : 2);
    const int ll = lane - g * 20;               // lanes with ll>=20 (60..63) are spares
    const int llc = min(ll, 19);
    const float di = dinv[node];
    const int n = cnt[node];
    const uint* XW32 = reinterpret_cast<const uint*>(XW);  // row stride 20 uints

    float a0 = 0.f, a1 = 0.f;
    for (int e = g; e < n; e += 3) {            // 3 edges in flight across lane groups
        const int s = colb[(size_t)node * BUCKET + e];
        const float w = dinv[s] * di;
        const uint p = XW32[(size_t)s * 20 + llc];
        a0 = fmaf(bflo(p), w, a0); a1 = fmaf(bfhi(p), w, a1);
    }
    // cross-group reduce to lanes 0..19
    const float t1 = __shfl(a0, lane + 20), t2 = __shfl(a0, lane + 40);
    const float u1 = __shfl(a1, lane + 20), u2 = __shfl(a1, lane + 40);
    float v0 = -INFINITY, v1 = -INFINITY;
    if (lane < 20) {
        const float s0 = a0 + t1 + t2, s1 = a1 + u1 + u2;
        const uint ps = XW32[(size_t)node * 20 + lane];
        const float ws = di * di;
        v0 = fmaf(bflo(ps), ws, s0) + bias[2 * lane];
        v1 = fmaf(bfhi(ps), ws, s1) + bias[2 * lane + 1];
    }
    float m = fmaxf(v0, v1);
#pragma unroll
    for (int o = 32; o > 0; o >>= 1) m = fmaxf(m, __shfl_xor(m, o));
    float s = (lane < 20) ? (expf(v0 - m) + expf(v1 - m)) : 0.f;
#pragma unroll
    for (int o = 32; o > 0; o >>= 1) s += __shfl_xor(s, o);
    if (lane < 20) {
        const float ls = m + logf(s);
        float2 r; r.x = v0 - ls; r.y = v1 - ls;
        reinterpret_cast<float2*>(out)[(size_t)node * 20 + lane] = r;
    }
}

extern "C" void kernel_launch(void* const* d_in, const int* in_sizes, int n_in,
                              void* d_out, int out_size, void* d_ws, size_t ws_size,
                              hipStream_t stream) {
    const float* x  = (const float*)d_in[0];
    const float* W1 = (const float*)d_in[1];
    const float* b1 = (const float*)d_in[2];
    const float* W2 = (const float*)d_in[3];
    const float* b2 = (const float*)d_in[4];
    const float* W3 = (const float*)d_in[5];
    const float* b3 = (const float*)d_in[6];
    const int* ei   = (const int*)d_in[7];
    const int* srcp = ei;
    const int* dstp = ei + N_EDGES;
    float* out = (float*)d_out;

    // workspace: cnt[50176] dinv[50176] colb[50000*64] B0[N*128 bf16] B1[N*128 bf16]
    int*    cnt  = (int*)d_ws;
    float*  dinv = (float*)(cnt + 50176);
    int*    colb = (int*)(dinv + 50176);
    ushort* B0   = (ushort*)(colb + (size_t)N_NODES * BUCKET);
    ushort* B1   = B0 + (size_t)N_NODES * 128;

    const int NB_N = (N_NODES + 255) / 256;   // 196
    const int NB_E = (N_EDGES + 255) / 256;   // 3125
    const int NB_W = (N_NODES * 64) / 256;    // 12500 (one wave per node)
    const int NB_G = (N_NODES / 16 + 15) / 16;  // 196 gemm blocks (16 tiles each)

    // bucketed CSR + norms
    zero_cnt_k<<<NB_N, 256, 0, stream>>>(cnt);
    scatter_k<<<NB_E, 256, 0, stream>>>(srcp, dstp, cnt, colb);
    dinv_k<<<NB_N, 256, 0, stream>>>(cnt, dinv);

    // layer 1 (A = x, fp32 -> convert inline)
    gemm_mfma_k<8, true><<<NB_G, 512, 0, stream>>>(x, W1, B1, 128);
    gather128_k<true><<<NB_W, 256, 0, stream>>>(B1, cnt, colb, dinv, b1, B0);
    // layer 2
    gemm_mfma_k<8, false><<<NB_G, 512, 0, stream>>>(B0, W2, B1, 128);
    gather128_k<true><<<NB_W, 256, 0, stream>>>(B1, cnt, colb, dinv, b2, B0);
    // layer 3 (fout=40) + fused log-softmax
    gemm_mfma_k<3, false><<<NB_G, 512, 0, stream>>>(B0, W3, B1, 40);
    gather40_lsm_k<<<NB_W, 256, 0, stream>>>(B1, cnt, colb, dinv, b3, out);
}

// Round 5
// 275.208 us; speedup vs baseline: 43.8654x; 1.0842x over previous
//
#include <hip/hip_runtime.h>
#include <math.h>

#define N_NODES 50000
#define N_EDGES 800000
#define BUCKET 64
#define GEMM_BLKS 196   // ceil(3125 row-tiles / 16)
#define SCAT_BLKS 391   // ceil(200000 scatter threads / 512)
// F_IN = HID = 128, C = 40

typedef __attribute__((ext_vector_type(8))) short short8;
typedef __attribute__((ext_vector_type(4))) float f32x4;

__device__ __forceinline__ ushort f2bf(float f) {
    union { float f; uint u; } v; v.f = f;
    uint r = v.u + 0x7FFFu + ((v.u >> 16) & 1u);  // RNE
    return (ushort)(r >> 16);
}
__device__ __forceinline__ float bflo(uint p) {
    union { uint u; float f; } v; v.u = p << 16; return v.f;
}
__device__ __forceinline__ float bfhi(uint p) {
    union { uint u; float f; } v; v.u = p & 0xFFFF0000u; return v.f;
}

__global__ void dinv_k(const int* __restrict__ cnt, float* __restrict__ dinv) {
    int i = blockIdx.x * 256 + threadIdx.x;
    if (i < N_NODES) dinv[i] = rsqrtf((float)(cnt[i] + 1));  // +1 self-loop
}

// ---------------- fused: gemm1 (MFMA, fp32->bf16 inline) + bucketed scatter ----------------
// blocks [0, GEMM_BLKS): Y[N x 128](bf16) = cvt(A[N x 128] f32) @ W[128 x 128]
// blocks [GEMM_BLKS, GEMM_BLKS+SCAT_BLKS): scatter edges into fixed 64-slot buckets, 4 edges/thread
__global__ __launch_bounds__(512) void fused_gemm1_scatter_k(
        const float* __restrict__ Af, const float* __restrict__ W, ushort* __restrict__ Y,
        const int* __restrict__ src, const int* __restrict__ dst,
        int* __restrict__ cnt, int* __restrict__ colb) {
    constexpr int NT = 8;
    __shared__ ushort sB[4 * NT * 64 * 8];
    const int tid = threadIdx.x;

    if (blockIdx.x >= GEMM_BLKS) {
        // ---- scatter role ----
        const int t = (blockIdx.x - GEMM_BLKS) * 512 + tid;
        if (t >= N_EDGES / 4) return;
        const int4 s4 = reinterpret_cast<const int4*>(src)[t];
        const int4 d4 = reinterpret_cast<const int4*>(dst)[t];
        int p0 = atomicAdd(&cnt[d4.x], 1);
        int p1 = atomicAdd(&cnt[d4.y], 1);
        int p2 = atomicAdd(&cnt[d4.z], 1);
        int p3 = atomicAdd(&cnt[d4.w], 1);
        colb[(size_t)d4.x * BUCKET + p0] = s4.x;
        colb[(size_t)d4.y * BUCKET + p1] = s4.y;
        colb[(size_t)d4.z * BUCKET + p2] = s4.z;
        colb[(size_t)d4.w * BUCKET + p3] = s4.w;
        return;
    }

    // ---- gemm role ----
    constexpr int FP = NT * 16;
    for (int i = tid; i < 128 * FP; i += 512) {
        const int k = i / FP, n = i % FP;           // coalesced W read
        const int s = k >> 5, r2 = (k >> 3) & 3, j = k & 7;
        const int t = n >> 4, nl = n & 15;
        const int l = r2 * 16 + nl;
        const int lp = (l & 56) | ((l + (l >> 3)) & 7);
        sB[(((s * NT + t) * 64) + lp) * 8 + j] = f2bf(W[k * 128 + n]);
    }
    __syncthreads();

    const int wid = tid >> 6, lane = tid & 63;
    const int lp = (lane & 56) | ((lane + (lane >> 3)) & 7);
    const int t0 = blockIdx.x * 16 + wid * 2;
    const int t1 = t0 + 1;
    const int t0c = min(t0, N_NODES / 16 - 1);
    const int t1c = min(t1, N_NODES / 16 - 1);

    f32x4 acc[2][NT];
#pragma unroll
    for (int u = 0; u < 2; u++)
#pragma unroll
        for (int t = 0; t < NT; t++) acc[u][t] = (f32x4){0.f, 0.f, 0.f, 0.f};

#pragma unroll
    for (int s = 0; s < 4; s++) {
        short8 a0, a1;
        const int ko = 32 * s + 8 * (lane >> 4);
        const float4* p0 = reinterpret_cast<const float4*>(Af + (size_t)(t0c * 16 + (lane & 15)) * 128 + ko);
        const float4* p1 = reinterpret_cast<const float4*>(Af + (size_t)(t1c * 16 + (lane & 15)) * 128 + ko);
        float4 u0 = p0[0], u1 = p0[1], v0 = p1[0], v1 = p1[1];
        a0[0] = f2bf(u0.x); a0[1] = f2bf(u0.y); a0[2] = f2bf(u0.z); a0[3] = f2bf(u0.w);
        a0[4] = f2bf(u1.x); a0[5] = f2bf(u1.y); a0[6] = f2bf(u1.z); a0[7] = f2bf(u1.w);
        a1[0] = f2bf(v0.x); a1[1] = f2bf(v0.y); a1[2] = f2bf(v0.z); a1[3] = f2bf(v0.w);
        a1[4] = f2bf(v1.x); a1[5] = f2bf(v1.y); a1[6] = f2bf(v1.z); a1[7] = f2bf(v1.w);
#pragma unroll
        for (int t = 0; t < NT; t++) {
            short8 b = *reinterpret_cast<const short8*>(&sB[(((s * NT + t) * 64) + lp) * 8]);
            acc[0][t] = __builtin_amdgcn_mfma_f32_16x16x32_bf16(a0, b, acc[0][t], 0, 0, 0);
            acc[1][t] = __builtin_amdgcn_mfma_f32_16x16x32_bf16(a1, b, acc[1][t], 0, 0, 0);
        }
    }

    const int rl = 4 * (lane >> 4), cl = lane & 15;
#pragma unroll
    for (int u = 0; u < 2; u++) {
        const int tile = u ? t1 : t0;
        if (tile >= N_NODES / 16) continue;
        const int row0 = tile * 16;
#pragma unroll
        for (int t = 0; t < NT; t++) {
            const int c = 16 * t + cl;
#pragma unroll
            for (int g = 0; g < 4; g++)
                Y[(size_t)(row0 + rl + g) * 128 + c] = f2bf(acc[u][t][g]);
        }
    }
}

// ---------------- MFMA GEMM (layers 2,3): Y[N x fout](bf16) = A[N x 128](bf16) @ W ----------------
template <int NT>
__global__ __launch_bounds__(512) void gemm_mfma_k(const ushort* __restrict__ Ab,
                                                   const float* __restrict__ W,
                                                   ushort* __restrict__ Y,
                                                   const int fout) {
    __shared__ ushort sB[4 * NT * 64 * 8];
    const int tid = threadIdx.x;
    constexpr int FP = NT * 16;
    for (int i = tid; i < 128 * FP; i += 512) {
        const int k = i / FP, n = i % FP;
        const int s = k >> 5, r2 = (k >> 3) & 3, j = k & 7;
        const int t = n >> 4, nl = n & 15;
        const int l = r2 * 16 + nl;
        const int lp = (l & 56) | ((l + (l >> 3)) & 7);
        sB[(((s * NT + t) * 64) + lp) * 8 + j] = (n < fout) ? f2bf(W[k * fout + n]) : (ushort)0;
    }
    __syncthreads();

    const int wid = tid >> 6, lane = tid & 63;
    const int lp = (lane & 56) | ((lane + (lane >> 3)) & 7);
    const int t0 = blockIdx.x * 16 + wid * 2;
    const int t1 = t0 + 1;
    const int t0c = min(t0, N_NODES / 16 - 1);
    const int t1c = min(t1, N_NODES / 16 - 1);

    f32x4 acc[2][NT];
#pragma unroll
    for (int u = 0; u < 2; u++)
#pragma unroll
        for (int t = 0; t < NT; t++) acc[u][t] = (f32x4){0.f, 0.f, 0.f, 0.f};

#pragma unroll
    for (int s = 0; s < 4; s++) {
        const int ko = 32 * s + 8 * (lane >> 4);
        short8 a0 = *reinterpret_cast<const short8*>(Ab + (size_t)(t0c * 16 + (lane & 15)) * 128 + ko);
        short8 a1 = *reinterpret_cast<const short8*>(Ab + (size_t)(t1c * 16 + (lane & 15)) * 128 + ko);
#pragma unroll
        for (int t = 0; t < NT; t++) {
            short8 b = *reinterpret_cast<const short8*>(&sB[(((s * NT + t) * 64) + lp) * 8]);
            acc[0][t] = __builtin_amdgcn_mfma_f32_16x16x32_bf16(a0, b, acc[0][t], 0, 0, 0);
            acc[1][t] = __builtin_amdgcn_mfma_f32_16x16x32_bf16(a1, b, acc[1][t], 0, 0, 0);
        }
    }

    const int rl = 4 * (lane >> 4), cl = lane & 15;
#pragma unroll
    for (int u = 0; u < 2; u++) {
        const int tile = u ? t1 : t0;
        if (tile >= N_NODES / 16) continue;
        const int row0 = tile * 16;
#pragma unroll
        for (int t = 0; t < NT; t++) {
            const int c = 16 * t + cl;
            if (NT == 3 && c >= fout) continue;
#pragma unroll
            for (int g = 0; g < 4; g++)
                Y[(size_t)(row0 + rl + g) * fout + c] = f2bf(acc[u][t][g]);
        }
    }
}

// ---------------- fused aggregation (F=128): one wave/node, 4-edge unroll ----------------
template <bool RELU>
__global__ __launch_bounds__(256) void gather128_k(const ushort* __restrict__ XW,
                                                   const int* __restrict__ cnt,
                                                   const int* __restrict__ colb,
                                                   const float* __restrict__ dinv,
                                                   const float* __restrict__ bias,
                                                   ushort* __restrict__ out) {
    const int node = (blockIdx.x * 256 + threadIdx.x) >> 6;
    const int lane = threadIdx.x & 63;
    if (node >= N_NODES) return;
    const float di = dinv[node];
    const int n = cnt[node];
    const int4* bucket = reinterpret_cast<const int4*>(colb + (size_t)node * BUCKET);
    const uint* XW32 = reinterpret_cast<const uint*>(XW);  // row stride 64 uints

    float a0 = 0.f, a1 = 0.f, b0 = 0.f, b1 = 0.f;
    float c0 = 0.f, c1 = 0.f, d0 = 0.f, d1 = 0.f;
    int e = 0;
    for (; e + 4 <= n; e += 4) {
        const int4 s4 = bucket[e >> 2];
        const float w0 = dinv[s4.x] * di, w1 = dinv[s4.y] * di;
        const float w2 = dinv[s4.z] * di, w3 = dinv[s4.w] * di;
        const uint p0 = XW32[(size_t)s4.x * 64 + lane];
        const uint p1 = XW32[(size_t)s4.y * 64 + lane];
        const uint p2 = XW32[(size_t)s4.z * 64 + lane];
        const uint p3 = XW32[(size_t)s4.w * 64 + lane];
        a0 = fmaf(bflo(p0), w0, a0); a1 = fmaf(bfhi(p0), w0, a1);
        b0 = fmaf(bflo(p1), w1, b0); b1 = fmaf(bfhi(p1), w1, b1);
        c0 = fmaf(bflo(p2), w2, c0); c1 = fmaf(bfhi(p2), w2, c1);
        d0 = fmaf(bflo(p3), w3, d0); d1 = fmaf(bfhi(p3), w3, d1);
    }
    for (; e < n; e++) {
        const int s = colb[(size_t)node * BUCKET + e];
        const float w = dinv[s] * di;
        const uint p = XW32[(size_t)s * 64 + lane];
        a0 = fmaf(bflo(p), w, a0); a1 = fmaf(bfhi(p), w, a1);
    }
    const uint ps = XW32[(size_t)node * 64 + lane];
    const float ws = di * di;
    a0 = fmaf(bflo(ps), ws, (a0 + b0) + (c0 + d0)) + bias[2 * lane];
    a1 = fmaf(bfhi(ps), ws, (a1 + b1) + (c1 + d1)) + bias[2 * lane + 1];
    if (RELU) { a0 = fmaxf(a0, 0.f); a1 = fmaxf(a1, 0.f); }
    reinterpret_cast<uint*>(out)[(size_t)node * 64 + lane] =
        (uint)f2bf(a0) | ((uint)f2bf(a1) << 16);
}

// ---------------- layer 3: gather (F=40) + log-softmax, 3 edge-groups per wave ----------------
__global__ __launch_bounds__(256) void gather40_lsm_k(const ushort* __restrict__ XW,
                                                      const int* __restrict__ cnt,
                                                      const int* __restrict__ colb,
                                                      const float* __restrict__ dinv,
                                                      const float* __restrict__ bias,
                                                      float* __restrict__ out) {
    const int node = (blockIdx.x * 256 + threadIdx.x) >> 6;
    const int lane = threadIdx.x & 63;
    if (node >= N_NODES) return;
    const int g = lane < 20 ? 0 : (lane < 40 ? 1 : 2);
    const int ll = lane - g * 20;
    const int llc = min(ll, 19);
    const float di = dinv[node];
    const int n = cnt[node];
    const uint* XW32 = reinterpret_cast<const uint*>(XW);  // row stride 20 uints

    float a0 = 0.f, a1 = 0.f;
    for (int e = g; e < n; e += 3) {
        const int s = colb[(size_t)node * BUCKET + e];
        const float w = dinv[s] * di;
        const uint p = XW32[(size_t)s * 20 + llc];
        a0 = fmaf(bflo(p), w, a0); a1 = fmaf(bfhi(p), w, a1);
    }
    const float t1 = __shfl(a0, lane + 20), t2 = __shfl(a0, lane + 40);
    const float u1 = __shfl(a1, lane + 20), u2 = __shfl(a1, lane + 40);
    float v0 = -INFINITY, v1 = -INFINITY;
    if (lane < 20) {
        const float s0 = a0 + t1 + t2, s1 = a1 + u1 + u2;
        const uint ps = XW32[(size_t)node * 20 + lane];
        const float ws = di * di;
        v0 = fmaf(bflo(ps), ws, s0) + bias[2 * lane];
        v1 = fmaf(bfhi(ps), ws, s1) + bias[2 * lane + 1];
    }
    float m = fmaxf(v0, v1);
#pragma unroll
    for (int o = 32; o > 0; o >>= 1) m = fmaxf(m, __shfl_xor(m, o));
    float s = (lane < 20) ? (expf(v0 - m) + expf(v1 - m)) : 0.f;
#pragma unroll
    for (int o = 32; o > 0; o >>= 1) s += __shfl_xor(s, o);
    if (lane < 20) {
        const float ls = m + logf(s);
        float2 r; r.x = v0 - ls; r.y = v1 - ls;
        reinterpret_cast<float2*>(out)[(size_t)node * 20 + lane] = r;
    }
}

extern "C" void kernel_launch(void* const* d_in, const int* in_sizes, int n_in,
                              void* d_out, int out_size, void* d_ws, size_t ws_size,
                              hipStream_t stream) {
    const float* x  = (const float*)d_in[0];
    const float* W1 = (const float*)d_in[1];
    const float* b1 = (const float*)d_in[2];
    const float* W2 = (const float*)d_in[3];
    const float* b2 = (const float*)d_in[4];
    const float* W3 = (const float*)d_in[5];
    const float* b3 = (const float*)d_in[6];
    const int* ei   = (const int*)d_in[7];
    const int* srcp = ei;
    const int* dstp = ei + N_EDGES;
    float* out = (float*)d_out;

    // workspace: cnt[50176] dinv[50176] colb[50000*64] B0[N*128 bf16] B1[N*128 bf16]
    int*    cnt  = (int*)d_ws;
    float*  dinv = (float*)(cnt + 50176);
    int*    colb = (int*)(dinv + 50176);
    ushort* B0   = (ushort*)(colb + (size_t)N_NODES * BUCKET);
    ushort* B1   = B0 + (size_t)N_NODES * 128;

    const int NB_N = (N_NODES + 255) / 256;   // 196
    const int NB_W = (N_NODES * 64) / 256;    // 12500 (one wave per node)

    // cnt = 0 (graph-capture-legal async memset), then fused gemm1 + scatter
    hipMemsetAsync(cnt, 0, 50176 * sizeof(int), stream);
    fused_gemm1_scatter_k<<<GEMM_BLKS + SCAT_BLKS, 512, 0, stream>>>(
        x, W1, B1, srcp, dstp, cnt, colb);
    dinv_k<<<NB_N, 256, 0, stream>>>(cnt, dinv);

    // layer 1 aggregation
    gather128_k<true><<<NB_W, 256, 0, stream>>>(B1, cnt, colb, dinv, b1, B0);
    // layer 2
    gemm_mfma_k<8><<<GEMM_BLKS, 512, 0, stream>>>(B0, W2, B1, 128);
    gather128_k<true><<<NB_W, 256, 0, stream>>>(B1, cnt, colb, dinv, b2, B0);
    // layer 3 (fout=40) + fused log-softmax
    gemm_mfma_k<3><<<GEMM_BLKS, 512, 0, stream>>>(B0, W3, B1, 40);
    gather40_lsm_k<<<NB_W, 256, 0, stream>>>(B1, cnt, colb, dinv, b3, out);
}